// Round 6
// baseline (469.710 us; speedup 1.0000x reference)
//
#include <hip/hip_runtime.h>

// VQ-VAE vector quantizer, MI355X.
// z_e: [32,64,32,32] f32, codebook: [1024,64] f32.
// d_out = q_out(2097152) | loss(1) | perplexity(1) | encodings(33554432), all f32.
//
// Pipeline (3 dispatches):
//   1. vq_ensq_kernel    : codebook squared norms + hist zero
//   2. vq_argmin_kernel  : fused distances+argmin+q_out+loss+hist+encodings
//   3. vq_finalize_kernel: loss mean + perplexity
//
// argmin structure (round 6): lane PAIR per row (32 z-regs/lane, halves the
// register footprint that made the allocator park z in AGPRs in r4/r5), codebook
// fed by per-lane f32x4 VMEM loads (in-order vmcnt -> deep pipelining, unlike
// SMEM's out-of-order lgkmcnt(0) full drains). 8 waves = 4 k-splits x 2 rowgrps.
//
// ws layout (4-byte units):
//   [0,1024)       hist (int)
//   [1024,2048)    ensq (float)
//   [34816,35328)  partials (float[512])

#define NROWS 32768
#define KC    1024
#define DD    64
#define HW    1024
#define CHW   65536

typedef float f32x2 __attribute__((ext_vector_type(2)));
typedef float f32x4 __attribute__((ext_vector_type(4)));

__global__ __launch_bounds__(256) void vq_ensq_kernel(const float* __restrict__ cb,
                                                      float* __restrict__ ensq,
                                                      int* __restrict__ hist) {
  int k = blockIdx.x * 256 + threadIdx.x;   // 4 blocks x 256 = exactly KC
  hist[k] = 0;
  const float* row = cb + k * DD;
  float s = 0.f;
#pragma unroll
  for (int c = 0; c < DD; ++c) s = fmaf(row[c], row[c], s);
  ensq[k] = s;
}

__global__ __launch_bounds__(512)
__attribute__((amdgpu_waves_per_eu(4, 4)))
void vq_argmin_kernel(
    const float* __restrict__ z_e, const float* __restrict__ cb,
    const float* __restrict__ ensq_g, float* __restrict__ qout,
    float* __restrict__ enc, int* __restrict__ hist,
    float* __restrict__ partials) {
  __shared__ float s_val[8][32];
  __shared__ int   s_idx[8][32];
  __shared__ int   s_final[64];
  __shared__ float s_loss[8];

  const int tid  = threadIdx.x;
  const int lane = tid & 63;
  const int wave = __builtin_amdgcn_readfirstlane(tid >> 6);  // wave-uniform
  const int ks   = wave & 3;    // k-split: codes [ks*256, ks*256+256)
  const int rg   = wave >> 2;   // row group 0/1 (rows rg*32..rg*32+32)
  const int rloc = lane >> 1;   // row within group
  const int half = lane & 1;    // c-half: [0,32) or [32,64)
  const int n    = blockIdx.x * 64 + rg * 32 + rloc;
  const int b    = n >> 10;
  const int hw   = n & (HW - 1);
  const float* zp = z_e + (size_t)b * CHW + hw + ((size_t)(half * 32) << 10);

  // this lane's half-row: 32 VGPRs. asm pin: compiler cannot rematerialize
  // the loads inside the K-loop.
  float z[32];
#pragma unroll
  for (int i = 0; i < 32; ++i) {
    z[i] = zp[(size_t)i << 10];
    asm volatile("" : "+v"(z[i]));
  }

  // ||z||^2: per-half sequential chain, then pair-combine (a+b == b+a in IEEE,
  // both lanes get identical bits).
  float zh = 0.f;
#pragma unroll
  for (int i = 0; i < 32; ++i) zh = fmaf(z[i], z[i], zh);
  const float zsq = zh + __shfl_xor(zh, 1, 64);

  // Streaming zero-fill of this block's encodings slice (64 rows x 1024 =
  // 256 KB): one 8B nontemporal store per thread per K-group (64 groups).
  f32x2* myenc = (f32x2*)(enc + (size_t)blockIdx.x * 64 * KC) + tid;

  const int kbase = ks * 256;
  float bestd = 3.402823466e38f;
  int   besti = 0;

  for (int kk = 0; kk < 256; kk += 4) {
    {
      f32x2 zz = {0.f, 0.f};
      __builtin_nontemporal_store(zz, &myenc[(kk >> 2) * 512]);
    }
    const int kg = kbase + kk;
    // per-lane halves of 4 code rows; even/odd lanes read the two 16B halves
    // -> 2 broadcast transactions per load instr, vmcnt-pipelined.
    const f32x4* p0 = (const f32x4*)(cb + (size_t)(kg + 0) * DD + half * 32);
    const f32x4* p1 = (const f32x4*)(cb + (size_t)(kg + 1) * DD + half * 32);
    const f32x4* p2 = (const f32x4*)(cb + (size_t)(kg + 2) * DD + half * 32);
    const f32x4* p3 = (const f32x4*)(cb + (size_t)(kg + 3) * DD + half * 32);
    float s0 = 0.f, s1 = 0.f, s2 = 0.f, s3 = 0.f;
#pragma unroll
    for (int i = 0; i < 8; ++i) {
      f32x4 e0 = p0[i], e1 = p1[i], e2 = p2[i], e3 = p3[i];
#pragma unroll
      for (int m = 0; m < 4; ++m) {
        float zc = z[i * 4 + m];
        s0 = fmaf(zc, e0[m], s0);
        s1 = fmaf(zc, e1[m], s1);
        s2 = fmaf(zc, e2[m], s2);
        s3 = fmaf(zc, e3[m], s3);
      }
    }
    // combine halves (both lanes of the pair end with identical full dots)
    s0 = s0 + __shfl_xor(s0, 1, 64);
    s1 = s1 + __shfl_xor(s1, 1, 64);
    s2 = s2 + __shfl_xor(s2, 1, 64);
    s3 = s3 + __shfl_xor(s3, 1, 64);
    // mimic ref rounding: (||z||^2 + ||e||^2) - 2*(z.e), all fp32
    float d0 = (zsq + ensq_g[kg + 0]) - 2.f * s0;
    float d1 = (zsq + ensq_g[kg + 1]) - 2.f * s1;
    float d2 = (zsq + ensq_g[kg + 2]) - 2.f * s2;
    float d3 = (zsq + ensq_g[kg + 3]) - 2.f * s3;
    if (d0 < bestd) { bestd = d0; besti = kg + 0; }
    if (d1 < bestd) { bestd = d1; besti = kg + 1; }
    if (d2 < bestd) { bestd = d2; besti = kg + 2; }
    if (d3 < bestd) { bestd = d3; besti = kg + 3; }
  }

  if (half == 0) {
    s_val[wave][rloc] = bestd;
    s_idx[wave][rloc] = besti;
  }
  __syncthreads();   // also drains (vmcnt 0) the zero-fill stores

  // cross-k-split argmin reduce (ascending code ranges; tie -> lower index),
  // one-hot scatter and histogram. Waves 0 and 4 reduce their row group.
  if ((wave == 0 || wave == 4) && lane < 32) {
    const int w0 = wave;
    float bd = s_val[w0][lane];
    int   bi = s_idx[w0][lane];
#pragma unroll
    for (int w2 = 1; w2 < 4; ++w2) {
      float d  = s_val[w0 + w2][lane];
      int   i2 = s_idx[w0 + w2][lane];
      if (d < bd || (d == bd && i2 < bi)) { bd = d; bi = i2; }
    }
    const int row = (w0 >> 2) * 32 + lane;
    s_final[row] = bi;
    atomicAdd(&hist[bi], 1);
    enc[(size_t)(blockIdx.x * 64 + row) * KC + bi] = 1.0f;
  }
  __syncthreads();

  // fused epilogue: q_out write + loss partial. Row = lane; each wave handles
  // 8 channels for all 64 rows. z reloaded from global (L1/L2-hot).
  const int bif = s_final[lane];
  const int n2  = blockIdx.x * 64 + lane;
  const int b2  = n2 >> 10;
  const int hw2 = n2 & (HW - 1);
  const float* zp2   = z_e + (size_t)b2 * CHW + hw2;
  const float* cbrow = cb + (size_t)bif * DD;
  float* qp = qout + (size_t)b2 * CHW + hw2;
  float lacc = 0.f;
#pragma unroll
  for (int j = 0; j < 8; ++j) {
    int c = wave * 8 + j;
    float v    = cbrow[c];
    float zc   = zp2[(size_t)c << 10];
    float diff = v - zc;               // matches ref (quantized - ze)
    qp[(size_t)c << 10] = zc + diff;   // matches ref ze + (quantized - ze)
    lacc = fmaf(diff, diff, lacc);
  }
#pragma unroll
  for (int off = 32; off > 0; off >>= 1) lacc += __shfl_down(lacc, off, 64);
  if (lane == 0) s_loss[wave] = lacc;
  __syncthreads();
  if (tid == 0) {
    float t = 0.f;
#pragma unroll
    for (int w2 = 0; w2 < 8; ++w2) t += s_loss[w2];
    partials[blockIdx.x] = t;
  }
}

__global__ __launch_bounds__(1024) void vq_finalize_kernel(
    const int* __restrict__ hist, const float* __restrict__ partials,
    float* __restrict__ out_loss, float* __restrict__ out_ppl) {
  __shared__ float red[1024];
  const int t = threadIdx.x;

  // entropy term
  float p   = (float)hist[t] * (1.0f / 32768.0f);
  float ent = p * logf(p + 1e-10f);
  red[t] = ent;
  __syncthreads();
  for (int s = 512; s > 0; s >>= 1) {
    if (t < s) red[t] += red[t + s];
    __syncthreads();
  }
  float entropy = red[0];
  __syncthreads();

  // loss sum
  red[t] = (t < 512) ? partials[t] : 0.f;
  __syncthreads();
  for (int s = 512; s > 0; s >>= 1) {
    if (t < s) red[t] += red[t + s];
    __syncthreads();
  }
  if (t == 0) {
    *out_loss = 0.25f * (red[0] * (1.0f / 2097152.0f));
    *out_ppl  = expf(-entropy);
  }
}

extern "C" void kernel_launch(void* const* d_in, const int* in_sizes, int n_in,
                              void* d_out, int out_size, void* d_ws, size_t ws_size,
                              hipStream_t stream) {
  const float* z_e = (const float*)d_in[0];
  const float* cb  = (const float*)d_in[1];

  float* out  = (float*)d_out;
  float* qout = out;                       // 2097152
  float* loss = out + 2097152;
  float* ppl  = out + 2097153;
  float* enc  = out + 2097154;             // 33554432 floats

  int*   hist     = (int*)d_ws;
  float* ensq     = (float*)d_ws + 1024;
  float* partials = (float*)d_ws + 34816;

  vq_ensq_kernel<<<4, 256, 0, stream>>>(cb, ensq, hist);
  vq_argmin_kernel<<<512, 512, 0, stream>>>(z_e, cb, ensq, qout, enc, hist, partials);
  vq_finalize_kernel<<<1, 1024, 0, stream>>>(hist, partials, loss, ppl);
}

// Round 7
// 106.015 us; speedup vs baseline: 4.4306x; 4.4306x over previous
//
#include <hip/hip_runtime.h>

// VQ-VAE vector quantizer, MI355X.
// z_e: [32,64,32,32] f32, codebook: [1024,64] f32.
// d_out = q_out(2097152) | loss(1) | perplexity(1) | encodings(33554432), all f32.
//
// Pipeline (3 dispatches):
//   1. vq_ensq_kernel    : codebook squared norms + hist zero
//   2. vq_argmin_kernel  : fused distances+argmin+q_out+loss+hist+encodings
//   3. vq_finalize_kernel: loss mean + perplexity
//
// argmin structure (round 7): back to z[64]-resident + SGPR codebook feed
// (scalar pipe is the ONLY broadcast-operand path that doesn't contend with
// VALU or the single per-CU LDS pipe; round 1 = LDS-bound, round 6 = L1-bound).
// The r3-r5 pathology (allocator parks z in AGPRs / remats, 50% of VALU =
// copies) is killed by per-FMA inline asm: "v" constraints on acc+z and "s"
// on the codebook element make AGPR-parking cost a copy PER USE in the
// allocator's model, so z[64] stays in arch VGPRs.
//
// ws layout (4-byte units):
//   [0,1024)       hist (int)
//   [1024,2048)    ensq (float)
//   [34816,35328)  partials (float[512])

#define NROWS 32768
#define KC    1024
#define DD    64
#define HW    1024
#define CHW   65536
#define WAVES 8           // 512 threads/block, 8-way K split (128 codes/wave)

typedef float f32x2 __attribute__((ext_vector_type(2)));

__global__ __launch_bounds__(256) void vq_ensq_kernel(const float* __restrict__ cb,
                                                      float* __restrict__ ensq,
                                                      int* __restrict__ hist) {
  int k = blockIdx.x * 256 + threadIdx.x;   // 4 blocks x 256 = exactly KC
  hist[k] = 0;
  const float* row = cb + k * DD;
  float s = 0.f;
#pragma unroll
  for (int c = 0; c < DD; ++c) s = fmaf(row[c], row[c], s);
  ensq[k] = s;
}

__global__ __launch_bounds__(512)
__attribute__((amdgpu_waves_per_eu(4, 4)))
void vq_argmin_kernel(
    const float* __restrict__ z_e, const float* __restrict__ cb,
    const float* __restrict__ ensq_g, float* __restrict__ qout,
    float* __restrict__ enc, int* __restrict__ hist,
    float* __restrict__ partials) {
  __shared__ float s_val[WAVES][64];
  __shared__ int   s_idx[WAVES][64];
  __shared__ float s_loss[WAVES];

  const int tid  = threadIdx.x;
  const int lane = tid & 63;
  const int wave = __builtin_amdgcn_readfirstlane(tid >> 6);  // wave-uniform
  const int n    = blockIdx.x * 64 + lane;
  const int b    = n >> 10;
  const int hw   = n & (HW - 1);
  const float* zp = z_e + (size_t)b * CHW + hw;

  // this thread's z vector: 64 VGPRs, coalesced loads (lanes = consecutive hw).
  // asm pin: opaque result -> no remat of the loads inside the K-loop.
  float z[DD];
#pragma unroll
  for (int c = 0; c < DD; ++c) {
    z[c] = zp[(size_t)c << 10];
    asm volatile("" : "+v"(z[c]));
  }

  float zsq = 0.f;
#pragma unroll
  for (int c = 0; c < DD; ++c) zsq = fmaf(z[c], z[c], zsq);

  // Streaming zero-fill of this block's encodings slice (64 rows x 1024 =
  // 256 KB): one 8B nontemporal store per thread per K-group (64 groups).
  f32x2* myenc = (f32x2*)(enc + (size_t)blockIdx.x * 64 * KC) + tid;

  // This wave scans codes [kbase, kbase+128), 2 codes per group (2 interleaved
  // fmac chains; 4-cycle dep gap == v_fmac latency). Codebook elements are
  // wave-uniform -> s_load; each v_fmac_f32 reads 1 SGPR + 1 VGPR (legal VOP2).
  const int kbase = wave * (KC / WAVES);
  float bestd = 3.402823466e38f;
  int   besti = 0;

  for (int kk = 0; kk < KC / WAVES; kk += 2) {
    {
      f32x2 zz = {0.f, 0.f};
      __builtin_nontemporal_store(zz, &myenc[(kk >> 1) * 512]);
    }
    const int kg = kbase + kk;
    const float* p0 = cb + (size_t)(kg + 0) * DD;
    const float* p1 = cb + (size_t)(kg + 1) * DD;
    float s0 = 0.f, s1 = 0.f;
#pragma unroll
    for (int c = 0; c < DD; ++c) {
      float e0 = p0[c];   // uniform -> SGPR (s_load, scalar pipe)
      float e1 = p1[c];
      asm("v_fmac_f32 %0, %2, %3\n\t"
          "v_fmac_f32 %1, %4, %5"
          : "+v"(s0), "+v"(s1)
          : "s"(e0), "v"(z[c]), "s"(e1), "v"(z[c]));
    }
    // mimic ref rounding: (||z||^2 + ||e||^2) - 2*(z.e), all fp32
    float d0 = (zsq + ensq_g[kg + 0]) - 2.f * s0;
    float d1 = (zsq + ensq_g[kg + 1]) - 2.f * s1;
    if (d0 < bestd) { bestd = d0; besti = kg + 0; }
    if (d1 < bestd) { bestd = d1; besti = kg + 1; }
  }

  s_val[wave][lane] = bestd;
  s_idx[wave][lane] = besti;
  __syncthreads();   // also drains (vmcnt 0) the zero-fill stores

  // cross-wave argmin reduce (first-min tie-break on lower index) + the
  // one-hot 1.0 scatter (zeros for these addresses completed at the barrier)
  if (wave == 0) {
    float bd = s_val[0][lane];
    int   bi = s_idx[0][lane];
#pragma unroll
    for (int w2 = 1; w2 < WAVES; ++w2) {
      float d  = s_val[w2][lane];
      int   i2 = s_idx[w2][lane];
      if (d < bd || (d == bd && i2 < bi)) { bd = d; bi = i2; }
    }
    s_idx[0][lane] = bi;   // broadcast final index
    atomicAdd(&hist[bi], 1);
    enc[(size_t)n * KC + bi] = 1.0f;
  }
  __syncthreads();

  // fused epilogue: q_out write + loss partial. Each wave handles 8 channels
  // for all 64 rows of the block. z reloaded from global (L1/L2-hot) to avoid
  // runtime-indexing the z[] register array (scratch spill, rule #20).
  const int bif = s_idx[0][lane];
  const float* cbrow = cb + (size_t)bif * DD;
  float* qp = qout + (size_t)b * CHW + hw;
  float lacc = 0.f;
#pragma unroll
  for (int j = 0; j < DD / WAVES; ++j) {
    int c = wave * (DD / WAVES) + j;
    float v    = cbrow[c];
    float zc   = zp[(size_t)c << 10];
    float diff = v - zc;               // matches ref (quantized - ze)
    qp[(size_t)c << 10] = zc + diff;   // matches ref ze + (quantized - ze)
    lacc = fmaf(diff, diff, lacc);
  }
#pragma unroll
  for (int off = 32; off > 0; off >>= 1) lacc += __shfl_down(lacc, off, 64);
  if (lane == 0) s_loss[wave] = lacc;
  __syncthreads();
  if (tid == 0) {
    float t = 0.f;
#pragma unroll
    for (int w2 = 0; w2 < WAVES; ++w2) t += s_loss[w2];
    partials[blockIdx.x] = t;
  }
}

__global__ __launch_bounds__(1024) void vq_finalize_kernel(
    const int* __restrict__ hist, const float* __restrict__ partials,
    float* __restrict__ out_loss, float* __restrict__ out_ppl) {
  __shared__ float red[1024];
  const int t = threadIdx.x;

  // entropy term
  float p   = (float)hist[t] * (1.0f / 32768.0f);
  float ent = p * logf(p + 1e-10f);
  red[t] = ent;
  __syncthreads();
  for (int s = 512; s > 0; s >>= 1) {
    if (t < s) red[t] += red[t + s];
    __syncthreads();
  }
  float entropy = red[0];
  __syncthreads();

  // loss sum
  red[t] = (t < 512) ? partials[t] : 0.f;
  __syncthreads();
  for (int s = 512; s > 0; s >>= 1) {
    if (t < s) red[t] += red[t + s];
    __syncthreads();
  }
  if (t == 0) {
    *out_loss = 0.25f * (red[0] * (1.0f / 2097152.0f));
    *out_ppl  = expf(-entropy);
  }
}

extern "C" void kernel_launch(void* const* d_in, const int* in_sizes, int n_in,
                              void* d_out, int out_size, void* d_ws, size_t ws_size,
                              hipStream_t stream) {
  const float* z_e = (const float*)d_in[0];
  const float* cb  = (const float*)d_in[1];

  float* out  = (float*)d_out;
  float* qout = out;                       // 2097152
  float* loss = out + 2097152;
  float* ppl  = out + 2097153;
  float* enc  = out + 2097154;             // 33554432 floats

  int*   hist     = (int*)d_ws;
  float* ensq     = (float*)d_ws + 1024;
  float* partials = (float*)d_ws + 34816;

  vq_ensq_kernel<<<4, 256, 0, stream>>>(cb, ensq, hist);
  vq_argmin_kernel<<<512, 512, 0, stream>>>(z_e, cb, ensq, qout, enc, hist, partials);
  vq_finalize_kernel<<<1, 1024, 0, stream>>>(hist, partials, loss, ppl);
}